// Round 10
// baseline (474.993 us; speedup 1.0000x reference)
//
#include <hip/hip_runtime.h>
#include <cstdint>
#include <cstddef>

typedef unsigned short u16;
typedef float f32x4 __attribute__((ext_vector_type(4)));
typedef float f32x2 __attribute__((ext_vector_type(2)));
typedef short short8 __attribute__((ext_vector_type(8)));
typedef int i32x4 __attribute__((ext_vector_type(4)));

// ---------------- helpers ----------------

__device__ __forceinline__ float geluf(float v) {  // exact (libm erff)
  return 0.5f * v * (1.0f + erff(v * 0.70710678118654752440f));
}

// Abramowitz-Stegun 7.1.26: |err| <= 1.5e-7 abs.
__device__ __forceinline__ float erf_fast(float x) {
  const float ax = fabsf(x);
  const float t = __builtin_amdgcn_rcpf(fmaf(0.3275911f, ax, 1.0f));
  float p = fmaf(1.061405429f, t, -1.453152027f);
  p = fmaf(p, t, 1.421413741f);
  p = fmaf(p, t, -0.284496736f);
  p = fmaf(p, t, 0.254829592f);
  p = p * t;
  const float e = __expf(-ax * ax);
  const float r = fmaf(-p, e, 1.0f);
  return copysignf(r, x);
}
__device__ __forceinline__ float gelu_fast(float v) {
  return 0.5f * v * (1.0f + erf_fast(v * 0.70710678118654752440f));
}

// tanh-form gelu: |err vs erf-gelu| ~3e-4 abs — below bf16 storage quantum.
__device__ __forceinline__ float gelu_tanh(float x) {
  const float x2 = x * x;
  const float u = fmaf(0.044715f, x2, 1.0f);
  const float z = x * u * 2.3022077f;
  const float e = exp2f(z);
  const float r = __builtin_amdgcn_rcpf(e + 1.0f);
  return fmaf(-x, r, x);
}

__device__ __forceinline__ u16 f2bf(float f) {  // RNE fp32 -> bf16 bits
  unsigned u = __float_as_uint(f);
  u = (u + 0x7FFFu + ((u >> 16) & 1u)) >> 16;
  return (u16)u;
}
__device__ __forceinline__ float bf2f(u16 h) {
  return __uint_as_float(((unsigned)h) << 16);
}

__device__ __forceinline__ unsigned cvt_pk_bf16(float lo, float hi) {
  unsigned r;
  asm("v_cvt_pk_bf16_f32 %0, %1, %2" : "=v"(r) : "v"(lo), "v"(hi));
  return r;
}

// async global->LDS, 16B per lane; LDS dest must be WAVE-UNIFORM base
// (HW writes lane l at base + l*16).
typedef const __attribute__((address_space(1))) unsigned int ga_u32;
typedef __attribute__((address_space(3))) unsigned int la_u32;
__device__ __forceinline__ void gload_lds16(const u16* g, u16* l) {
  __builtin_amdgcn_global_load_lds((ga_u32*)g, (la_u32*)l, 16, 0, 0);
}

__device__ __forceinline__ void waveRed2(float& s, float& s2) {
#pragma unroll
  for (int m = 1; m < 64; m <<= 1) {
    s += __shfl_xor(s, m);
    s2 += __shfl_xor(s2, m);
  }
}

// ---------------- fused prep: nvphi(+stats) + converts + router-LN ----------------
__global__ __launch_bounds__(256) void k_prep(
    const float* __restrict__ nv, const float* __restrict__ pW1,
    const float* __restrict__ pb1, float* __restrict__ nvphi,
    float* __restrict__ nvstats, const float* __restrict__ pW2,
    u16* __restrict__ pW2T, const float* __restrict__ rW1,
    u16* __restrict__ rW1T, const float* __restrict__ rW2,
    u16* __restrict__ rW2T, const float* __restrict__ Wr2,
    u16* __restrict__ Wr2b, const float* __restrict__ Wr1,
    float* __restrict__ Wr1Tf, const float* __restrict__ x,
    const float* __restrict__ rn_g, const float* __restrict__ rn_b,
    float* __restrict__ xln) {
  __shared__ __align__(16) float sbuf[1536 + 96];
  const int b = blockIdx.x, tid = threadIdx.x;
  if (b < 256) {
    const int n0 = b * 8;
#pragma unroll
    for (int j = 0; j < 4; ++j) {
      const int e = tid + j * 256;  // e = k*128 + i
      sbuf[(e & 127) * 12 + (e >> 7)] = nv[n0 * 128 + e];
    }
    __syncthreads();
    float acc[8] = {};
#pragma unroll 2
    for (int i = 0; i < 128; ++i) {
      const float wv_ = pW1[i * 256 + tid];
      const f32x4 nA = *(const f32x4*)&sbuf[i * 12];
      const f32x4 nB = *(const f32x4*)&sbuf[i * 12 + 4];
      acc[0] = fmaf(nA[0], wv_, acc[0]);
      acc[1] = fmaf(nA[1], wv_, acc[1]);
      acc[2] = fmaf(nA[2], wv_, acc[2]);
      acc[3] = fmaf(nA[3], wv_, acc[3]);
      acc[4] = fmaf(nB[0], wv_, acc[4]);
      acc[5] = fmaf(nB[1], wv_, acc[5]);
      acc[6] = fmaf(nB[2], wv_, acc[6]);
      acc[7] = fmaf(nB[3], wv_, acc[7]);
    }
    const float pb = pb1[tid];
    const float wact = pW1[128 * 256 + tid];
    float* redN = sbuf + 1536;
#pragma unroll
    for (int kk = 0; kk < 8; ++kk) {
      const float s = acc[kk] + pb;
      nvphi[(size_t)(n0 + kk) * 256 + tid] = s;
      float a1 = s, a2 = s * s, a3 = s * wact;
#pragma unroll
      for (int m = 1; m < 64; m <<= 1) {
        a1 += __shfl_xor(a1, m);
        a2 += __shfl_xor(a2, m);
        a3 += __shfl_xor(a3, m);
      }
      if ((tid & 63) == 0) {
        const int w4 = tid >> 6;
        redN[w4 * 24 + kk * 3 + 0] = a1;
        redN[w4 * 24 + kk * 3 + 1] = a2;
        redN[w4 * 24 + kk * 3 + 2] = a3;
      }
    }
    __syncthreads();
    if (tid < 24) {
      const int kk = tid / 3, st = tid - kk * 3;
      const float v = redN[tid] + redN[24 + tid] + redN[48 + tid] + redN[72 + tid];
      nvstats[(size_t)(n0 + kk) * 4 + st] = v * (1.f / 256.f);
    } else if (tid < 32) {
      nvstats[(size_t)(n0 + tid - 24) * 4 + 3] = 0.f;
    }
  } else if (b < 512) {
    const int n = b - 256;
    pW2T[n * 256 + tid] = f2bf(pW2[tid * 256 + n]);
  } else if (b < 1024) {
    const int n = b - 512;
    rW1T[(size_t)n * 256 + tid] = f2bf(rW1[(size_t)tid * 512 + n]);
  } else if (b < 1536) {
    const int n = b - 1024;
    for (int k = tid; k < 512; k += 256)
      rW2T[(size_t)n * 512 + k] = f2bf(rW2[(size_t)k * 512 + n]);
  } else if (b < 5632) {
    const int i = (b - 1536) * 256 + tid;
    Wr2b[i] = f2bf(Wr2[i]);
  } else if (b < 6144) {
    // fp32 transpose of Wr1: Wr1Tf[k][n] = Wr1[n][k] (1 MB, L2-resident)
    const int k = b - 5632;
    Wr1Tf[(size_t)k * 512 + tid] = Wr1[(size_t)tid * 512 + k];
    Wr1Tf[(size_t)k * 512 + tid + 256] = Wr1[(size_t)(tid + 256) * 512 + k];
  } else {
    float* red = sbuf;
    const int t = b - 6144;
    const float v0 = x[(size_t)t * 512 + tid];
    const float v1 = x[(size_t)t * 512 + 256 + tid];
    float s = v0 + v1, s2 = v0 * v0 + v1 * v1;
    waveRed2(s, s2);
    if ((tid & 63) == 0) { red[(tid >> 6) * 2] = s; red[(tid >> 6) * 2 + 1] = s2; }
    __syncthreads();
    s = red[0] + red[2] + red[4] + red[6];
    s2 = red[1] + red[3] + red[5] + red[7];
    const float mu = s * (1.f / 512.f);
    const float var = fmaxf(s2 * (1.f / 512.f) - mu * mu, 0.f);
    const float rstd = 1.f / sqrtf(var + 1e-5f);
    xln[(size_t)t * 512 + tid] = (v0 - mu) * rstd * rn_g[tid] + rn_b[tid];
    xln[(size_t)t * 512 + 256 + tid] =
        (v1 - mu) * rstd * rn_g[tid + 256] + rn_b[tid + 256];
  }
}

// ---------------- 64x64 fp32 GEMM, C = act(A[M,K] @ BT[K,N]) ----------------
// R20 (kept): B straight from L2 (pre-transposed Wr1Tf); no Bs LDS.
// Per-output k-summation ascending-k fma -> h BIT-IDENTICAL (selection).
template <int GMODE, bool BF16OUT>
__global__ __launch_bounds__(256) void gemm8f(const float* __restrict__ A,
                                              const float* __restrict__ BT,
                                              float* __restrict__ C,
                                              u16* __restrict__ Cb, int M,
                                              int N, int K) {
  __shared__ float As[2][16][68];
  const int tid = threadIdx.x;
  const int tm = tid >> 4, tn = tid & 15;
  const int m0 = blockIdx.y * 64, n0 = blockIdx.x * 64;
  const int sr = tid >> 2, sk = (tid & 3) * 4;  // stage: 64 rows x 16 k
  const float* gA = &A[(size_t)(m0 + sr) * K + sk];
  float acc[4][4] = {};
  float4 a0 = *(const float4*)&gA[0];
  const int nk0 = K >> 4;
  int buf = 0;
  for (int it = 0; it < nk0; ++it) {
    As[buf][sk + 0][sr] = a0.x; As[buf][sk + 1][sr] = a0.y;
    As[buf][sk + 2][sr] = a0.z; As[buf][sk + 3][sr] = a0.w;
    __syncthreads();
    if (it + 1 < nk0) a0 = *(const float4*)&gA[(it + 1) * 16];
    float4 bbq[16];
#pragma unroll
    for (int k = 0; k < 16; ++k)
      bbq[k] = *(const float4*)&BT[(size_t)(it * 16 + k) * N + n0 + tn * 4];
#pragma unroll
    for (int k = 0; k < 16; ++k) {
      float a[4];
      *(float4*)&a[0] = *(const float4*)&As[buf][k][tm * 4];
      const float4 bb = bbq[k];
#pragma unroll
      for (int i = 0; i < 4; ++i) {
        acc[i][0] = fmaf(a[i], bb.x, acc[i][0]);
        acc[i][1] = fmaf(a[i], bb.y, acc[i][1]);
        acc[i][2] = fmaf(a[i], bb.z, acc[i][2]);
        acc[i][3] = fmaf(a[i], bb.w, acc[i][3]);
      }
    }
    buf ^= 1;
  }
#pragma unroll
  for (int i = 0; i < 4; ++i) {
    float4 o0;
    float* p0 = (float*)&o0;
#pragma unroll
    for (int j = 0; j < 4; ++j) {
      float xv = acc[i][j];
      if (GMODE == 1) xv = gelu_fast(xv);
      if (GMODE == 2) xv = geluf(xv);
      p0[j] = xv;
    }
    const size_t off = (size_t)(m0 + tm * 4 + i) * N + n0 + tn * 4;
    *(float4*)&C[off] = o0;
    if (BF16OUT) {
      ushort4 u0;
      u0.x = f2bf(p0[0]); u0.y = f2bf(p0[1]); u0.z = f2bf(p0[2]); u0.w = f2bf(p0[3]);
      *(ushort4*)&Cb[off] = u0;
    }
  }
}

// ---------------- MFMA GEMM: C = act(A[M,K] @ B[N,K]^T + bias) ----------------
// R20 (kept): 2x2 wave grid; gload_lds 2-phase double-buffer.
template <int GMODE, bool BIAS, int OUT, int NT>
__global__ __launch_bounds__(256) void gemm_mf(const u16* __restrict__ A,
                                               const u16* __restrict__ B,
                                               const float* __restrict__ bias,
                                               void* __restrict__ Cp, int M,
                                               int N, int K) {
  constexpr int ASZ = 64 * 32;        // u16
  constexpr int BSZ = NT * 32;        // u16
  constexpr int BUFSZ = ASZ + BSZ;
  constexpr int NTH = NT / 2;         // cols per wave
  constexpr int NCT = NT / 32;        // col-tiles per wave
  __shared__ __align__(16) u16 smem[2 * BUFSZ];

  const int tid = threadIdx.x;
  const int w = tid >> 6, lane = tid & 63;
  const int q = lane >> 4, c = lane & 15;
  const int wr = w & 1, wc = w >> 1;  // 2x2 wave grid
  const int m0 = blockIdx.y * 64, n0 = blockIdx.x * NT;
  const int lr = lane >> 2, lc = (lane & 3) * 8;
  const u16* gAs = A + (size_t)(m0 + w * 16 + lr) * K + lc;
  const u16* gBs = B + (size_t)(n0 + w * 16 + lr) * K + lc;
  const u16* gBs2 = B + (size_t)(n0 + (NT == 128 ? 64 : 0) + w * 16 + lr) * K + lc;

  f32x4 acc[2][NCT];
#pragma unroll
  for (int nt = 0; nt < NCT; ++nt) {
    const float bv = BIAS ? bias[n0 + wc * NTH + nt * 16 + c] : 0.f;
#pragma unroll
    for (int mt = 0; mt < 2; ++mt) acc[mt][nt] = (f32x4){bv, bv, bv, bv};
  }

  auto stage = [&](int b, int k0) {
    gload_lds16(gAs + k0, &smem[b * BUFSZ + w * 512]);
    gload_lds16(gBs + k0, &smem[b * BUFSZ + ASZ + w * 512]);
    if (NT == 128) gload_lds16(gBs2 + k0, &smem[b * BUFSZ + ASZ + (4 + w) * 512]);
  };

  stage(0, 0);
  __syncthreads();  // drains vmcnt -> buf0 ready
  int buf = 0;
  const int nk = K >> 5;
  for (int it = 0; it < nk; ++it) {
    if (it + 1 < nk) stage(buf ^ 1, (it + 1) * 32);  // async, in flight over MFMA
    short8 ah[2], bh[NCT];
#pragma unroll
    for (int mt = 0; mt < 2; ++mt)
      ah[mt] = *(const short8*)&smem[buf * BUFSZ + (wr * 32 + mt * 16 + c) * 32 + q * 8];
#pragma unroll
    for (int nt = 0; nt < NCT; ++nt)
      bh[nt] = *(const short8*)&smem[buf * BUFSZ + ASZ + (wc * NTH + nt * 16 + c) * 32 + q * 8];
#pragma unroll
    for (int mt = 0; mt < 2; ++mt)
#pragma unroll
      for (int nt = 0; nt < NCT; ++nt)
        acc[mt][nt] = __builtin_amdgcn_mfma_f32_16x16x32_bf16(ah[mt], bh[nt], acc[mt][nt], 0, 0, 0);
    __syncthreads();  // drains vmcnt -> buf^1 ready; readers of buf done
    buf ^= 1;
  }
#pragma unroll
  for (int mt = 0; mt < 2; ++mt)
#pragma unroll
    for (int nt = 0; nt < NCT; ++nt)
#pragma unroll
      for (int reg = 0; reg < 4; ++reg) {
        float v = acc[mt][nt][reg];
        if (GMODE == 1) v = gelu_fast(v);
        const size_t off =
            (size_t)(m0 + wr * 32 + mt * 16 + q * 4 + reg) * N + n0 + wc * NTH + nt * 16 + c;
        if (OUT == 0) ((float*)Cp)[off] = v;
        else          ((u16*)Cp)[off] = f2bf(v);
      }
}

// ---------------- fused: top-64 (approx+exact rescore) THEN act ----------------
// R22 (kept): x preloaded; rescore unroll 4; selection math byte-identical.
__global__ __launch_bounds__(256) void k_topk_act(
    const u16* __restrict__ scoresb, const float* __restrict__ h,
    const float* __restrict__ Wr2, const float* __restrict__ x,
    const float* __restrict__ W_in, int* __restrict__ idxout,
    float* __restrict__ act) {
  __shared__ __align__(16) float hs[512];
  __shared__ int redc[2][4];
  __shared__ int cand[160];
  __shared__ float cex[160];
  __shared__ int selidx[64];
  __shared__ unsigned ccnt;
  const int t = blockIdx.x, tid = threadIdx.x;
  // preload x (consumed by act phase much later; latency fully hidden)
  const float xv0 = x[(size_t)t * 512 + tid];
  const float xv1 = x[(size_t)t * 512 + 256 + tid];
  hs[tid] = h[(size_t)t * 512 + tid];
  hs[tid + 256] = h[(size_t)t * 512 + 256 + tid];
  unsigned key[8];
#pragma unroll
  for (int j = 0; j < 8; ++j) {
    const unsigned u = (unsigned)scoresb[(size_t)t * 2048 + tid + 256 * j];
    key[j] = (u & 0x8000u) ? (0xFFFFu & ~u) : (u | 0x8000u);
  }
  if (tid == 0) ccnt = 0u;
  unsigned lo = 0u, hi = 0xFFFFu;
  int pb = 0;
  while (lo < hi) {
    const unsigned mid = (lo + hi + 1u) >> 1;
    int c = 0;
#pragma unroll
    for (int j = 0; j < 8; ++j) c += (key[j] >= mid);
#pragma unroll
    for (int m = 1; m < 64; m <<= 1) c += __shfl_xor(c, m);
    if ((tid & 63) == 0) redc[pb][tid >> 6] = c;
    __syncthreads();
    const int total = redc[pb][0] + redc[pb][1] + redc[pb][2] + redc[pb][3];
    if (total >= 96) lo = mid; else hi = mid - 1;
    pb ^= 1;
  }
#pragma unroll
  for (int j = 0; j < 8; ++j) {
    if (key[j] >= lo) {
      const unsigned pos = atomicAdd(&ccnt, 1u);
      if (pos < 160u) cand[pos] = tid + 256 * j;
    }
  }
  __syncthreads();
  const int cnt = (int)(ccnt < 160u ? ccnt : 160u);
  // exact fp32 rescore (summation order byte-identical to R18-R22)
  const int wv = tid >> 6, l = tid & 63;
#pragma unroll 4
  for (int ci = wv; ci < cnt; ci += 4) {
    const float* Wr = Wr2 + (size_t)cand[ci] * 512;
    float s = 0.f;
#pragma unroll
    for (int j = 0; j < 8; ++j) s = fmaf(Wr[l + 64 * j], hs[l + 64 * j], s);
#pragma unroll
    for (int m = 1; m < 64; m <<= 1) s += __shfl_xor(s, m);
    if (l == 0) cex[ci] = s;
  }
  __syncthreads();  // all hs(h) reads done -> safe to overwrite with x below
  hs[tid] = xv0;
  hs[tid + 256] = xv1;
  if (tid < cnt) {
    const float my = cex[tid];
    const int myi = cand[tid];
    int rank = 0;
    for (int j = 0; j < cnt; ++j) {
      const float oj = cex[j];
      const int oi = cand[j];
      rank += (oj > my) || (oj == my && oi < myi);
    }
    if (rank < 64) {
      selidx[rank] = myi;
      idxout[(size_t)t * 64 + rank] = myi;
    }
  }
  __syncthreads();
  // ---- Part 2: act; 16-lane groups, 4 rows in flight per wave ----
  const int g = l >> 4, l16 = l & 15;
#pragma unroll
  for (int qq = 0; qq < 4; ++qq) {
    const int k = wv * 16 + qq * 4 + g;
    const int n = selidx[k];
    const float* Wr = W_in + (size_t)n * 512 + l16 * 4;
    const float* xp = hs + l16 * 4;
    float s = 0.f;
#pragma unroll
    for (int j = 0; j < 8; ++j) {
      const float4 wa = *(const float4*)&Wr[j * 64];
      const float4 xa = *(const float4*)&xp[j * 64];
      s = fmaf(wa.x, xa.x, s);
      s = fmaf(wa.y, xa.y, s);
      s = fmaf(wa.z, xa.z, s);
      s = fmaf(wa.w, xa.w, s);
    }
    s += __shfl_xor(s, 1);
    s += __shfl_xor(s, 2);
    s += __shfl_xor(s, 4);
    s += __shfl_xor(s, 8);
    if (l16 == 0) act[(size_t)t * 64 + k] = gelu_fast(s);
  }
}

// ---------------- fused phi + rho-LN (one token per block) ----------------
// R23: LDS diet to EXACTLY 32768B -> 5 blocks/CU (was 34816 -> 4; LDS was
// the occupancy cap with ~34% stall). (a) h1s pad dropped (stride 264->256),
// replaced by 16B-chunk XOR swizzle chunk' = chunk ^ (row&7) on BOTH the
// Phase-A writes and Phase-B reads — bank quads spread as q^(c&7) -> 8
// lanes/quad, same 8-cycle floor as the old pad. (b) Phase-C transpose
// scratch split into two half-row passes (2x[32][66] = 16896B per pass).
// (c) rowstats/aggb/red aliased inside h1s. Math bit-identical to R16.
__global__ __launch_bounds__(256, 5) void k_phi(
    const float* __restrict__ nvphi, const float* __restrict__ nvstats,
    const float* __restrict__ pW1, const float* __restrict__ pln1_g,
    const float* __restrict__ pln1_b, const u16* __restrict__ pW2T,
    const float* __restrict__ pb2, const float* __restrict__ pln2_g,
    const float* __restrict__ pln2_b, const int* __restrict__ idx,
    const float* __restrict__ act, const float* __restrict__ rln_g,
    const float* __restrict__ rln_b, u16* __restrict__ rh) {
  __shared__ __align__(16) u16 h1s[64 * 256];  // 32768B exactly; ALL scratch aliased
  const int tid = threadIdx.x;
  const int t = blockIdx.x;
  const int w = tid >> 6, lane = tid & 63;
  const int q = lane >> 4, c = lane & 15;
  const int c8 = c & 7;
  // ---- Phase A: h1 = bf16(gelu(LN1(nvphi[n] + act*pW1[128,:]))) ----
  {
    int n_pre[4];
    float a_pre[4];
#pragma unroll
    for (int rd = 0; rd < 4; ++rd) {
      n_pre[rd] = idx[(size_t)t * 64 + w * 16 + rd * 4 + q];
      a_pre[rd] = act[(size_t)t * 64 + w * 16 + rd * 4 + q];
    }
    f32x4 w4[4], g1[4], b1[4];
#pragma unroll
    for (int j = 0; j < 4; ++j) {
      w4[j] = *(const f32x4*)&pW1[128 * 256 + c * 16 + j * 4];
      g1[j] = *(const f32x4*)&pln1_g[c * 16 + j * 4];
      b1[j] = *(const f32x4*)&pln1_b[c * 16 + j * 4];
    }
    float sw = 0.f, sw2 = 0.f;
#pragma unroll
    for (int j = 0; j < 4; ++j)
#pragma unroll
      for (int u = 0; u < 4; ++u) {
        sw += w4[j][u];
        sw2 = fmaf(w4[j][u], w4[j][u], sw2);
      }
#pragma unroll
    for (int m = 1; m < 16; m <<= 1) {
      sw += __shfl_xor(sw, m);
      sw2 += __shfl_xor(sw2, m);
    }
    const float mw = sw * (1.f / 256.f), e2w = sw2 * (1.f / 256.f);
    f32x4 stc = *(const f32x4*)&nvstats[n_pre[0] * 4];
    f32x4 nvc[4];
#pragma unroll
    for (int j = 0; j < 4; ++j)
      nvc[j] = *(const f32x4*)&nvphi[(size_t)n_pre[0] * 256 + c * 16 + j * 4];
#pragma unroll
    for (int rd = 0; rd < 4; ++rd) {
      f32x4 stn;
      f32x4 nvn[4];
      if (rd < 3) {
        stn = *(const f32x4*)&nvstats[n_pre[rd + 1] * 4];
#pragma unroll
        for (int j = 0; j < 4; ++j)
          nvn[j] = *(const f32x4*)&nvphi[(size_t)n_pre[rd + 1] * 256 + c * 16 + j * 4];
      }
      const int p = w * 16 + rd * 4 + q;
      const float a = a_pre[rd];
      const float mu = fmaf(a, mw, stc.x);
      const float e2 = fmaf(a * a, e2w, fmaf(a + a, stc.z, stc.y));
      const float var = fmaxf(e2 - mu * mu, 0.f);
      const float rstd = 1.f / sqrtf(var + 1e-5f);
      const float nmr = -mu * rstd;
      unsigned pk[8];
#pragma unroll
      for (int j = 0; j < 4; ++j) {
        float hh[4];
#pragma unroll
        for (int u = 0; u < 4; ++u) {
          const float v = fmaf(a, w4[j][u], nvc[j][u]);
          const float tt = fmaf(v, rstd, nmr);
          hh[u] = gelu_tanh(fmaf(tt, g1[j][u], b1[j][u]));
        }
        pk[j * 2] = cvt_pk_bf16(hh[0], hh[1]);
        pk[j * 2 + 1] = cvt_pk_bf16(hh[2], hh[3]);
      }
      // swizzled 16B-chunk writes: chunk' = chunk ^ (p&7)
      const int p8 = p & 7;
      *(i32x4*)&h1s[p * 256 + (((2 * c) ^ p8) << 3)] =
          (i32x4){(int)pk[0], (int)pk[1], (int)pk[2], (int)pk[3]};
      *(i32x4*)&h1s[p * 256 + (((2 * c + 1) ^ p8) << 3)] =
          (i32x4){(int)pk[4], (int)pk[5], (int)pk[6], (int)pk[7]};
      if (rd < 3) {
        stc = stn;
#pragma unroll
        for (int j = 0; j < 4; ++j) nvc[j] = nvn[j];
      }
    }
  }
  // ---- Phase B: acc[mt][nt] rows mt*16+q*4+reg, cols w*64+nt*16+c ----
  const u16* Bb = pW2T + ((size_t)(w * 64 + c) << 8) + q * 8;
  short8 be[4], bo[4];
#pragma unroll
  for (int nt = 0; nt < 4; ++nt) be[nt] = *(const short8*)&Bb[nt * 4096];
#pragma unroll
  for (int nt = 0; nt < 4; ++nt) bo[nt] = *(const short8*)&Bb[nt * 4096 + 32];
  f32x4 acc[4][4];
#pragma unroll
  for (int nt = 0; nt < 4; ++nt) {
    const float bz = pb2[w * 64 + nt * 16 + c];
#pragma unroll
    for (int mt = 0; mt < 4; ++mt) acc[mt][nt] = (f32x4){bz, bz, bz, bz};
  }
  __syncthreads();  // B2 (h1s read cross-wave below)
#pragma unroll
  for (int ks2 = 0; ks2 < 4; ++ks2) {
    {  // even ks: chunk = 8*ks2 + q
      short8 av[4];
#pragma unroll
      for (int mt = 0; mt < 4; ++mt)
        av[mt] = *(const short8*)&h1s[(mt * 16 + c) * 256 + (((ks2 * 8 + q) ^ c8) << 3)];
#pragma unroll
      for (int mt = 0; mt < 4; ++mt)
#pragma unroll
        for (int nt = 0; nt < 4; ++nt)
          acc[mt][nt] =
              __builtin_amdgcn_mfma_f32_16x16x32_bf16(av[mt], be[nt], acc[mt][nt], 0, 0, 0);
      if (ks2 < 3) {
#pragma unroll
        for (int nt = 0; nt < 4; ++nt)
          be[nt] = *(const short8*)&Bb[nt * 4096 + ks2 * 64 + 64];
      }
    }
    {  // odd ks: chunk = 8*ks2 + 4 + q
      short8 av[4];
#pragma unroll
      for (int mt = 0; mt < 4; ++mt)
        av[mt] = *(const short8*)&h1s[(mt * 16 + c) * 256 + (((ks2 * 8 + 4 + q) ^ c8) << 3)];
#pragma unroll
      for (int mt = 0; mt < 4; ++mt)
#pragma unroll
        for (int nt = 0; nt < 4; ++nt)
          acc[mt][nt] =
              __builtin_amdgcn_mfma_f32_16x16x32_bf16(av[mt], bo[nt], acc[mt][nt], 0, 0, 0);
      if (ks2 < 3) {
#pragma unroll
        for (int nt = 0; nt < 4; ++nt)
          bo[nt] = *(const short8*)&Bb[nt * 4096 + ks2 * 64 + 96];
      }
    }
  }
  __syncthreads();  // B3 (h1s reads done; alias as scratch)
  // ---- Phase C: LN2 stats via 2 half-row transpose passes (fits 32KB) ----
  float* sbuf = (float*)h1s;        // [32][66]
  float* s2buf = sbuf + 32 * 66;    // [32][66]; ends at float 4224 (16896B)
  float* rowstats = sbuf + 64 * 66; // 128 floats @ 4224
  float* aggb = rowstats + 128;     // 256 floats @ 4352
  float* redf = aggb + 256;         // 8 floats  @ 4608
#pragma unroll
  for (int half = 0; half < 2; ++half) {
#pragma unroll
    for (int mt2 = 0; mt2 < 2; ++mt2) {
      const int mt = half * 2 + mt2;
#pragma unroll
      for (int reg = 0; reg < 4; ++reg) {
        const float v0 = acc[mt][0][reg], v1 = acc[mt][1][reg];
        const float v2 = acc[mt][2][reg], v3 = acc[mt][3][reg];
        const float s = (v0 + v1) + (v2 + v3);
        float s2 = v0 * v0;
        s2 = fmaf(v1, v1, s2);
        s2 = fmaf(v2, v2, s2);
        s2 = fmaf(v3, v3, s2);
        const int rl = mt2 * 16 + q * 4 + reg;  // 0..31 local
        sbuf[rl * 66 + w * 16 + c] = s;
        s2buf[rl * 66 + w * 16 + c] = s2;
      }
    }
    __syncthreads();
    if (tid < 128) {
      const int rl = tid >> 2, seg = tid & 3;
      const float* rp = &sbuf[rl * 66 + seg * 16];
      const float* rp2 = &s2buf[rl * 66 + seg * 16];
      float ss = 0.f, ss2 = 0.f;
#pragma unroll
      for (int j = 0; j < 8; ++j) {
        const f32x2 u = *(const f32x2*)&rp[j * 2];
        const f32x2 u2 = *(const f32x2*)&rp2[j * 2];
        ss += u[0] + u[1];
        ss2 += u2[0] + u2[1];
      }
      ss += __shfl_xor(ss, 1);
      ss2 += __shfl_xor(ss2, 1);
      ss += __shfl_xor(ss, 2);
      ss2 += __shfl_xor(ss2, 2);
      if (seg == 0) {
        const float mu = ss * (1.f / 256.f);
        const float var = fmaxf(ss2 * (1.f / 256.f) - mu * mu, 0.f);
        const float rstd = 1.f / sqrtf(var + 1e-5f);
        rowstats[(half * 32 + rl) * 2] = mu;
        rowstats[(half * 32 + rl) * 2 + 1] = rstd;
      }
    }
    __syncthreads();
  }
  // ---- LN2 apply + k-sum ----
  float g2v[4], b2v[4], aggl[4];
#pragma unroll
  for (int nt = 0; nt < 4; ++nt) {
    g2v[nt] = pln2_g[w * 64 + nt * 16 + c];
    b2v[nt] = pln2_b[w * 64 + nt * 16 + c];
    aggl[nt] = 16.f * b2v[nt];
  }
#pragma unroll
  for (int mt = 0; mt < 4; ++mt)
#pragma unroll
    for (int reg = 0; reg < 4; ++reg) {
      const int r = mt * 16 + q * 4 + reg;
      const f32x2 mr = *(const f32x2*)&rowstats[r * 2];
      const float nmr = -mr[0] * mr[1];
#pragma unroll
      for (int nt = 0; nt < 4; ++nt) {
        const float tt = fmaf(acc[mt][nt][reg], mr[1], nmr);
        aggl[nt] = fmaf(tt, g2v[nt], aggl[nt]);
      }
    }
#pragma unroll
  for (int nt = 0; nt < 4; ++nt) {
    float vs = aggl[nt];
    vs += __shfl_xor(vs, 16);
    vs += __shfl_xor(vs, 32);
    if (q == 0) aggb[w * 64 + nt * 16 + c] = vs;
  }
  __syncthreads();  // B6
  // ---- fused rho-LN over 256 ----
  const float v = aggb[tid];
  float s = v, s2 = v * v;
  waveRed2(s, s2);
  if ((tid & 63) == 0) { redf[(tid >> 6) * 2] = s; redf[(tid >> 6) * 2 + 1] = s2; }
  __syncthreads();  // B7
  s = redf[0] + redf[2] + redf[4] + redf[6];
  s2 = redf[1] + redf[3] + redf[5] + redf[7];
  const float mu = s * (1.f / 256.f);
  const float var = fmaxf(s2 * (1.f / 256.f) - mu * mu, 0.f);
  const float rstd = 1.f / sqrtf(var + 1e-5f);
  rh[(size_t)t * 256 + tid] = f2bf((v - mu) * rstd * rln_g[tid] + rln_b[tid]);
}

// ---------------- launch ----------------
extern "C" void kernel_launch(void* const* d_in, const int* in_sizes, int n_in,
                              void* d_out, int out_size, void* d_ws, size_t ws_size,
                              hipStream_t stream) {
  const float* x = (const float*)d_in[0];
  const float* W_in = (const float*)d_in[1];
  const float* nv = (const float*)d_in[2];
  const float* Wr1 = (const float*)d_in[3];
  const float* Wr2 = (const float*)d_in[4];
  const float* rn_g = (const float*)d_in[5];
  const float* rn_b = (const float*)d_in[6];
  const float* pW1 = (const float*)d_in[7];
  const float* pb1 = (const float*)d_in[8];
  const float* pln1_g = (const float*)d_in[9];
  const float* pln1_b = (const float*)d_in[10];
  const float* pW2 = (const float*)d_in[11];
  const float* pb2 = (const float*)d_in[12];
  const float* pln2_g = (const float*)d_in[13];
  const float* pln2_b = (const float*)d_in[14];
  const float* rln_g = (const float*)d_in[15];
  const float* rln_b = (const float*)d_in[16];
  const float* rW1 = (const float*)d_in[17];
  const float* rb1 = (const float*)d_in[18];
  const float* rW2 = (const float*)d_in[19];
  const float* rb2 = (const float*)d_in[20];
  float* out = (float*)d_out;
  const int T = in_sizes[0] / 512;  // 4096

  float* ws = (float*)d_ws;
  float* xln = ws;    ws += (size_t)T * 512;
  float* h = ws;      ws += (size_t)T * 512;
  float* nvphi = ws;  ws += (size_t)2048 * 256;
  float* nvstats = ws; ws += (size_t)2048 * 4;
  float* Wr1Tf = ws;  ws += (size_t)512 * 512;
  float* actb = ws;   ws += (size_t)T * 64;
  int* idx = (int*)ws;   ws += (size_t)T * 64;
  u16* scoresb = (u16*)ws; ws += (size_t)T * 2048 / 2;
  u16* hb = (u16*)ws;    ws += (size_t)T * 512 / 2;
  u16* Wr2b = (u16*)ws;  ws += (size_t)2048 * 512 / 2;
  u16* pW2T = (u16*)ws;  ws += (size_t)2048 * 256 / 2;
  u16* rh = (u16*)ws;    ws += (size_t)T * 256 / 2;
  u16* t1b = (u16*)ws;   ws += (size_t)T * 512 / 2;
  u16* rW1T = (u16*)ws;  ws += (size_t)512 * 256 / 2;
  u16* rW2T = (u16*)ws;  ws += (size_t)512 * 512 / 2;

  k_prep<<<6144 + T, 256, 0, stream>>>(nv, pW1, pb1, nvphi, nvstats, pW2, pW2T,
                                       rW1, rW1T, rW2, rW2T, Wr2, Wr2b, Wr1,
                                       Wr1Tf, x, rn_g, rn_b, xln);
  gemm8f<2, true><<<dim3(512 / 64, T / 64), 256, 0, stream>>>(
      xln, Wr1Tf, h, hb, T, 512, 512);
  gemm_mf<0, false, 1, 128><<<dim3(2048 / 128, T / 64), 256, 0, stream>>>(
      hb, Wr2b, nullptr, scoresb, T, 2048, 512);
  k_topk_act<<<T, 256, 0, stream>>>(scoresb, h, Wr2, x, W_in, idx, actb);
  k_phi<<<T, 256, 0, stream>>>(nvphi, nvstats, pW1, pln1_g, pln1_b, pW2T, pb2,
                               pln2_g, pln2_b, idx, actb, rln_g, rln_b, rh);
  gemm_mf<1, true, 1, 64><<<dim3(512 / 64, T / 64), 256, 0, stream>>>(
      rh, rW1T, rb1, t1b, T, 512, 256);
  gemm_mf<0, true, 0, 64><<<dim3(512 / 64, T / 64), 256, 0, stream>>>(
      t1b, rW2T, rb2, out, T, 512, 512);
}

// Round 11
// 381.645 us; speedup vs baseline: 1.2446x; 1.2446x over previous
//
#include <hip/hip_runtime.h>
#include <cstdint>
#include <cstddef>

typedef unsigned short u16;
typedef float f32x4 __attribute__((ext_vector_type(4)));
typedef float f32x2 __attribute__((ext_vector_type(2)));
typedef short short8 __attribute__((ext_vector_type(8)));
typedef int i32x4 __attribute__((ext_vector_type(4)));

// ---------------- helpers ----------------

__device__ __forceinline__ float geluf(float v) {  // exact (libm erff)
  return 0.5f * v * (1.0f + erff(v * 0.70710678118654752440f));
}

// Abramowitz-Stegun 7.1.26: |err| <= 1.5e-7 abs.
__device__ __forceinline__ float erf_fast(float x) {
  const float ax = fabsf(x);
  const float t = __builtin_amdgcn_rcpf(fmaf(0.3275911f, ax, 1.0f));
  float p = fmaf(1.061405429f, t, -1.453152027f);
  p = fmaf(p, t, 1.421413741f);
  p = fmaf(p, t, -0.284496736f);
  p = fmaf(p, t, 0.254829592f);
  p = p * t;
  const float e = __expf(-ax * ax);
  const float r = fmaf(-p, e, 1.0f);
  return copysignf(r, x);
}
__device__ __forceinline__ float gelu_fast(float v) {
  return 0.5f * v * (1.0f + erf_fast(v * 0.70710678118654752440f));
}

// tanh-form gelu: |err vs erf-gelu| ~3e-4 abs — below bf16 storage quantum.
__device__ __forceinline__ float gelu_tanh(float x) {
  const float x2 = x * x;
  const float u = fmaf(0.044715f, x2, 1.0f);
  const float z = x * u * 2.3022077f;
  const float e = exp2f(z);
  const float r = __builtin_amdgcn_rcpf(e + 1.0f);
  return fmaf(-x, r, x);
}

__device__ __forceinline__ u16 f2bf(float f) {  // RNE fp32 -> bf16 bits
  unsigned u = __float_as_uint(f);
  u = (u + 0x7FFFu + ((u >> 16) & 1u)) >> 16;
  return (u16)u;
}
__device__ __forceinline__ float bf2f(u16 h) {
  return __uint_as_float(((unsigned)h) << 16);
}

__device__ __forceinline__ unsigned cvt_pk_bf16(float lo, float hi) {
  unsigned r;
  asm("v_cvt_pk_bf16_f32 %0, %1, %2" : "=v"(r) : "v"(lo), "v"(hi));
  return r;
}

// async global->LDS, 16B per lane; LDS dest must be WAVE-UNIFORM base
// (HW writes lane l at base + l*16). Completion tracked by vmcnt; the
// compiler's s_waitcnt vmcnt(0) before s_barrier (inside __syncthreads)
// is the drain point.
typedef const __attribute__((address_space(1))) unsigned int ga_u32;
typedef __attribute__((address_space(3))) unsigned int la_u32;
__device__ __forceinline__ void gload_lds16(const u16* g, u16* l) {
  __builtin_amdgcn_global_load_lds((ga_u32*)g, (la_u32*)l, 16, 0, 0);
}

__device__ __forceinline__ void waveRed2(float& s, float& s2) {
#pragma unroll
  for (int m = 1; m < 64; m <<= 1) {
    s += __shfl_xor(s, m);
    s2 += __shfl_xor(s2, m);
  }
}

// ---------------- fused prep: nvphi(+stats) + converts + router-LN ----------------
// R24 = revert to R18 config (best measured, 384.6us). R23 post-mortem:
// launch_bounds(256,5) on k_phi spilled the 64-reg MFMA accumulator to
// scratch (VGPR 48 + 224MB scratch writes) -> 4 blocks/CU is the hard cap.
__global__ __launch_bounds__(256) void k_prep(
    const float* __restrict__ nv, const float* __restrict__ pW1,
    const float* __restrict__ pb1, float* __restrict__ nvphi,
    float* __restrict__ nvstats, const float* __restrict__ pW2,
    u16* __restrict__ pW2T, const float* __restrict__ rW1,
    u16* __restrict__ rW1T, const float* __restrict__ rW2,
    u16* __restrict__ rW2T, const float* __restrict__ Wr2,
    u16* __restrict__ Wr2b, const float* __restrict__ x,
    const float* __restrict__ rn_g, const float* __restrict__ rn_b,
    float* __restrict__ xln) {
  __shared__ __align__(16) float sbuf[1536 + 96];
  const int b = blockIdx.x, tid = threadIdx.x;
  if (b < 256) {
    const int n0 = b * 8;
#pragma unroll
    for (int j = 0; j < 4; ++j) {
      const int e = tid + j * 256;  // e = k*128 + i
      sbuf[(e & 127) * 12 + (e >> 7)] = nv[n0 * 128 + e];
    }
    __syncthreads();
    float acc[8] = {};
#pragma unroll 2
    for (int i = 0; i < 128; ++i) {
      const float wv_ = pW1[i * 256 + tid];
      const f32x4 nA = *(const f32x4*)&sbuf[i * 12];
      const f32x4 nB = *(const f32x4*)&sbuf[i * 12 + 4];
      acc[0] = fmaf(nA[0], wv_, acc[0]);
      acc[1] = fmaf(nA[1], wv_, acc[1]);
      acc[2] = fmaf(nA[2], wv_, acc[2]);
      acc[3] = fmaf(nA[3], wv_, acc[3]);
      acc[4] = fmaf(nB[0], wv_, acc[4]);
      acc[5] = fmaf(nB[1], wv_, acc[5]);
      acc[6] = fmaf(nB[2], wv_, acc[6]);
      acc[7] = fmaf(nB[3], wv_, acc[7]);
    }
    const float pb = pb1[tid];
    const float wact = pW1[128 * 256 + tid];
    float* redN = sbuf + 1536;
#pragma unroll
    for (int kk = 0; kk < 8; ++kk) {
      const float s = acc[kk] + pb;
      nvphi[(size_t)(n0 + kk) * 256 + tid] = s;
      float a1 = s, a2 = s * s, a3 = s * wact;
#pragma unroll
      for (int m = 1; m < 64; m <<= 1) {
        a1 += __shfl_xor(a1, m);
        a2 += __shfl_xor(a2, m);
        a3 += __shfl_xor(a3, m);
      }
      if ((tid & 63) == 0) {
        const int w4 = tid >> 6;
        redN[w4 * 24 + kk * 3 + 0] = a1;
        redN[w4 * 24 + kk * 3 + 1] = a2;
        redN[w4 * 24 + kk * 3 + 2] = a3;
      }
    }
    __syncthreads();
    if (tid < 24) {
      const int kk = tid / 3, st = tid - kk * 3;
      const float v = redN[tid] + redN[24 + tid] + redN[48 + tid] + redN[72 + tid];
      nvstats[(size_t)(n0 + kk) * 4 + st] = v * (1.f / 256.f);
    } else if (tid < 32) {
      nvstats[(size_t)(n0 + tid - 24) * 4 + 3] = 0.f;
    }
  } else if (b < 512) {
    const int n = b - 256;
    pW2T[n * 256 + tid] = f2bf(pW2[tid * 256 + n]);
  } else if (b < 1024) {
    const int n = b - 512;
    rW1T[(size_t)n * 256 + tid] = f2bf(rW1[(size_t)tid * 512 + n]);
  } else if (b < 1536) {
    const int n = b - 1024;
    for (int k = tid; k < 512; k += 256)
      rW2T[(size_t)n * 512 + k] = f2bf(rW2[(size_t)k * 512 + n]);
  } else if (b < 5632) {
    const int i = (b - 1536) * 256 + tid;
    Wr2b[i] = f2bf(Wr2[i]);
  } else {
    float* red = sbuf;
    const int t = b - 5632;
    const float v0 = x[(size_t)t * 512 + tid];
    const float v1 = x[(size_t)t * 512 + 256 + tid];
    float s = v0 + v1, s2 = v0 * v0 + v1 * v1;
    waveRed2(s, s2);
    if ((tid & 63) == 0) { red[(tid >> 6) * 2] = s; red[(tid >> 6) * 2 + 1] = s2; }
    __syncthreads();
    s = red[0] + red[2] + red[4] + red[6];
    s2 = red[1] + red[3] + red[5] + red[7];
    const float mu = s * (1.f / 512.f);
    const float var = fmaxf(s2 * (1.f / 512.f) - mu * mu, 0.f);
    const float rstd = 1.f / sqrtf(var + 1e-5f);
    xln[(size_t)t * 512 + tid] = (v0 - mu) * rstd * rn_g[tid] + rn_b[tid];
    xln[(size_t)t * 512 + 256 + tid] =
        (v1 - mu) * rstd * rn_g[tid + 256] + rn_b[tid + 256];
  }
}

// ---------------- 128x64 fp32 GEMM, C = act(A[M,K] @ B[N,K]^T) ----------------
// R18 (best measured): 128x64 tile, 256 blocks, single-barrier double-buffer.
// Per-output k-summation order unchanged -> h bit-identical (selection).
template <int GMODE, bool BF16OUT>
__global__ __launch_bounds__(256) void gemm8f(const float* __restrict__ A,
                                              const float* __restrict__ B,
                                              float* __restrict__ C,
                                              u16* __restrict__ Cb, int M,
                                              int N, int K) {
  __shared__ float As[2][16][132];
  __shared__ float Bs[2][16][68];
  const int tid = threadIdx.x;
  const int tm = tid >> 4, tn = tid & 15;
  const int m0 = blockIdx.y * 128, n0 = blockIdx.x * 64;
  const int sr = tid >> 1, sk = (tid & 1) * 8;    // A stage: 128 rows x 8 k
  const int srB = tid >> 2, skB = (tid & 3) * 4;  // B stage: 64 rows x 4 k
  const float* gA = &A[(size_t)(m0 + sr) * K + sk];
  const float* gB = &B[(size_t)(n0 + srB) * K + skB];
  float acc[8][4] = {};
  float4 a0 = *(const float4*)&gA[0];
  float4 a1 = *(const float4*)&gA[4];
  float4 b0 = *(const float4*)&gB[0];
  const int nk0 = K >> 4;
  int buf = 0;
  for (int it = 0; it < nk0; ++it) {
    As[buf][sk + 0][sr] = a0.x; As[buf][sk + 1][sr] = a0.y; As[buf][sk + 2][sr] = a0.z; As[buf][sk + 3][sr] = a0.w;
    As[buf][sk + 4][sr] = a1.x; As[buf][sk + 5][sr] = a1.y; As[buf][sk + 6][sr] = a1.z; As[buf][sk + 7][sr] = a1.w;
    Bs[buf][skB + 0][srB] = b0.x; Bs[buf][skB + 1][srB] = b0.y; Bs[buf][skB + 2][srB] = b0.z; Bs[buf][skB + 3][srB] = b0.w;
    __syncthreads();
    if (it + 1 < nk0) {
      const int k0 = (it + 1) * 16;
      a0 = *(const float4*)&gA[k0];
      a1 = *(const float4*)&gA[k0 + 4];
      b0 = *(const float4*)&gB[k0];
    }
#pragma unroll
    for (int k = 0; k < 16; ++k) {
      float a[8], bb[4];
      *(float4*)&a[0] = *(const float4*)&As[buf][k][tm * 8];
      *(float4*)&a[4] = *(const float4*)&As[buf][k][tm * 8 + 4];
      *(float4*)&bb[0] = *(const float4*)&Bs[buf][k][tn * 4];
#pragma unroll
      for (int i = 0; i < 8; ++i)
#pragma unroll
        for (int j = 0; j < 4; ++j) acc[i][j] = fmaf(a[i], bb[j], acc[i][j]);
    }
    buf ^= 1;
  }
#pragma unroll
  for (int i = 0; i < 8; ++i) {
    float4 o0;
    float* p0 = (float*)&o0;
#pragma unroll
    for (int j = 0; j < 4; ++j) {
      float xv = acc[i][j];
      if (GMODE == 1) xv = gelu_fast(xv);
      if (GMODE == 2) xv = geluf(xv);
      p0[j] = xv;
    }
    const size_t off = (size_t)(m0 + tm * 8 + i) * N + n0 + tn * 4;
    *(float4*)&C[off] = o0;
    if (BF16OUT) {
      ushort4 u0;
      u0.x = f2bf(p0[0]); u0.y = f2bf(p0[1]); u0.z = f2bf(p0[2]); u0.w = f2bf(p0[3]);
      *(ushort4*)&Cb[off] = u0;
    }
  }
}

// ---------------- MFMA GEMM: C = act(A[M,K] @ B[N,K]^T + bias) ----------------
// R18 (best measured): 2-phase schedule — global_load_lds(16B) staging into
// double-buffered LINEAR LDS [row][32]; ONE barrier per 32-K step; stage of
// buf^1 issues BEFORE the MFMA cluster and drains at the barrier.
template <int GMODE, bool BIAS, int OUT, int NT>
__global__ __launch_bounds__(256) void gemm_mf(const u16* __restrict__ A,
                                               const u16* __restrict__ B,
                                               const float* __restrict__ bias,
                                               void* __restrict__ Cp, int M,
                                               int N, int K) {
  constexpr int ASZ = 64 * 32;        // u16
  constexpr int BSZ = NT * 32;        // u16
  constexpr int BUFSZ = ASZ + BSZ;
  __shared__ __align__(16) u16 smem[2 * BUFSZ];

  const int tid = threadIdx.x;
  const int w = tid >> 6, lane = tid & 63;
  const int q = lane >> 4, c = lane & 15;
  const int m0 = blockIdx.y * 64, n0 = blockIdx.x * NT;
  // staging: lane l covers row chunkbase + l/4, k-col (l%4)*8 (16B)
  const int lr = lane >> 2, lc = (lane & 3) * 8;
  const u16* gAs = A + (size_t)(m0 + w * 16 + lr) * K + lc;
  const u16* gBs = B + (size_t)(n0 + w * 16 + lr) * K + lc;
  const u16* gBs2 = B + (size_t)(n0 + (NT == 128 ? 64 : 0) + w * 16 + lr) * K + lc;

  f32x4 acc[NT / 16];
#pragma unroll
  for (int ct = 0; ct < NT / 16; ++ct) {
    const float bv = BIAS ? bias[n0 + ct * 16 + c] : 0.f;
    acc[ct] = (f32x4){bv, bv, bv, bv};
  }

  auto stage = [&](int b, int k0) {
    gload_lds16(gAs + k0, &smem[b * BUFSZ + w * 512]);
    gload_lds16(gBs + k0, &smem[b * BUFSZ + ASZ + w * 512]);
    if (NT == 128) gload_lds16(gBs2 + k0, &smem[b * BUFSZ + ASZ + (4 + w) * 512]);
  };

  stage(0, 0);
  __syncthreads();  // drains vmcnt -> buf0 ready
  int buf = 0;
  const int nk = K >> 5;
  for (int it = 0; it < nk; ++it) {
    if (it + 1 < nk) stage(buf ^ 1, (it + 1) * 32);  // async, in flight over MFMA
    const short8 ah = *(const short8*)&smem[buf * BUFSZ + (w * 16 + c) * 32 + q * 8];
#pragma unroll
    for (int ct = 0; ct < NT / 16; ++ct) {
      const short8 bh =
          *(const short8*)&smem[buf * BUFSZ + ASZ + (ct * 16 + c) * 32 + q * 8];
      acc[ct] = __builtin_amdgcn_mfma_f32_16x16x32_bf16(ah, bh, acc[ct], 0, 0, 0);
    }
    __syncthreads();  // drains vmcnt -> buf^1 ready; readers of buf done
    buf ^= 1;
  }
#pragma unroll
  for (int ct = 0; ct < NT / 16; ++ct) {
#pragma unroll
    for (int reg = 0; reg < 4; ++reg) {
      float v = acc[ct][reg];
      if (GMODE == 1) v = gelu_fast(v);
      const size_t off = (size_t)(m0 + w * 16 + q * 4 + reg) * N + n0 + ct * 16 + c;
      if (OUT == 0) ((float*)Cp)[off] = v;
      else          ((u16*)Cp)[off] = f2bf(v);
    }
  }
}

// ---------------- fused: top-64 (approx+exact rescore) THEN act ----------------
// R17/R18 (best measured). Selection math byte-identical across rounds.
__global__ __launch_bounds__(256) void k_topk_act(
    const u16* __restrict__ scoresb, const float* __restrict__ h,
    const float* __restrict__ Wr2, const float* __restrict__ x,
    const float* __restrict__ W_in, int* __restrict__ idxout,
    float* __restrict__ act) {
  __shared__ float hs[512];
  __shared__ int redc[2][4];
  __shared__ int cand[160];
  __shared__ float cex[160];
  __shared__ int selidx[64];
  __shared__ unsigned ccnt;
  const int t = blockIdx.x, tid = threadIdx.x;
  hs[tid] = h[(size_t)t * 512 + tid];
  hs[tid + 256] = h[(size_t)t * 512 + 256 + tid];
  unsigned key[8];
#pragma unroll
  for (int j = 0; j < 8; ++j) {
    const unsigned u = (unsigned)scoresb[(size_t)t * 2048 + tid + 256 * j];
    key[j] = (u & 0x8000u) ? (0xFFFFu & ~u) : (u | 0x8000u);
  }
  if (tid == 0) ccnt = 0u;
  unsigned lo = 0u, hi = 0xFFFFu;
  int pb = 0;
  while (lo < hi) {
    const unsigned mid = (lo + hi + 1u) >> 1;
    int c = 0;
#pragma unroll
    for (int j = 0; j < 8; ++j) c += (key[j] >= mid);
#pragma unroll
    for (int m = 1; m < 64; m <<= 1) c += __shfl_xor(c, m);
    if ((tid & 63) == 0) redc[pb][tid >> 6] = c;
    __syncthreads();
    const int total = redc[pb][0] + redc[pb][1] + redc[pb][2] + redc[pb][3];
    if (total >= 96) lo = mid; else hi = mid - 1;
    pb ^= 1;
  }
#pragma unroll
  for (int j = 0; j < 8; ++j) {
    if (key[j] >= lo) {
      const unsigned pos = atomicAdd(&ccnt, 1u);
      if (pos < 160u) cand[pos] = tid + 256 * j;
    }
  }
  __syncthreads();
  const int cnt = (int)(ccnt < 160u ? ccnt : 160u);
  const int wv = tid >> 6, l = tid & 63;
#pragma unroll 2
  for (int ci = wv; ci < cnt; ci += 4) {
    const float* Wr = Wr2 + (size_t)cand[ci] * 512;
    float s = 0.f;
#pragma unroll
    for (int j = 0; j < 8; ++j) s = fmaf(Wr[l + 64 * j], hs[l + 64 * j], s);
#pragma unroll
    for (int m = 1; m < 64; m <<= 1) s += __shfl_xor(s, m);
    if (l == 0) cex[ci] = s;
  }
  __syncthreads();
  if (tid < cnt) {
    const float my = cex[tid];
    const int myi = cand[tid];
    int rank = 0;
    for (int j = 0; j < cnt; ++j) {
      const float oj = cex[j];
      const int oi = cand[j];
      rank += (oj > my) || (oj == my && oi < myi);
    }
    if (rank < 64) {
      selidx[rank] = myi;
      idxout[(size_t)t * 64 + rank] = myi;
    }
  }
  __syncthreads();
  // ---- Part 2: act (reuse hs for x) ----
  hs[tid] = x[(size_t)t * 512 + tid];
  hs[tid + 256] = x[(size_t)t * 512 + 256 + tid];
  __syncthreads();
  const float4 xa = *(const float4*)&hs[l * 8];
  const float4 xb = *(const float4*)&hs[l * 8 + 4];
#pragma unroll 2
  for (int qq = 0; qq < 16; ++qq) {
    const int k = wv * 16 + qq;
    const int n = selidx[k];
    const float* Wr = W_in + (size_t)n * 512 + l * 8;
    const float4 wa = *(const float4*)Wr;
    const float4 wb = *(const float4*)(Wr + 4);
    float s = wa.x * xa.x;
    s = fmaf(wa.y, xa.y, s); s = fmaf(wa.z, xa.z, s); s = fmaf(wa.w, xa.w, s);
    s = fmaf(wb.x, xb.x, s); s = fmaf(wb.y, xb.y, s);
    s = fmaf(wb.z, xb.z, s); s = fmaf(wb.w, xb.w, s);
#pragma unroll
    for (int m = 1; m < 64; m <<= 1) s += __shfl_xor(s, m);
    if (l == 0) act[(size_t)t * 64 + k] = gelu_fast(s);
  }
}

// ---------------- fused phi + rho-LN (one token per block) ----------------
// R16 (locked, best measured): analytic LN1 stats; tanh-gelu; per-wave
// idx/act loads; Phase-A rd+1 prefetch; Phase-B double-buffered b-fragment
// prefetch. 34816B LDS + 128 total regs/wave (64 VGPR + 64 acc) -> 4
// blocks/CU is the hard occupancy cap (R23: (256,5) spilled acc to scratch).
__global__ __launch_bounds__(256, 4) void k_phi(
    const float* __restrict__ nvphi, const float* __restrict__ nvstats,
    const float* __restrict__ pW1, const float* __restrict__ pln1_g,
    const float* __restrict__ pln1_b, const u16* __restrict__ pW2T,
    const float* __restrict__ pb2, const float* __restrict__ pln2_g,
    const float* __restrict__ pln2_b, const int* __restrict__ idx,
    const float* __restrict__ act, const float* __restrict__ rln_g,
    const float* __restrict__ rln_b, u16* __restrict__ rh) {
  __shared__ __align__(16) u16 h1s[64 * 264];
  __shared__ float rowstats[64 * 2];
  __shared__ float red[8];
  const int tid = threadIdx.x;
  const int t = blockIdx.x;
  const int w = tid >> 6, lane = tid & 63;
  const int q = lane >> 4, c = lane & 15;
  {
    int n_pre[4];
    float a_pre[4];
#pragma unroll
    for (int rd = 0; rd < 4; ++rd) {
      n_pre[rd] = idx[(size_t)t * 64 + w * 16 + rd * 4 + q];
      a_pre[rd] = act[(size_t)t * 64 + w * 16 + rd * 4 + q];
    }
    f32x4 w4[4], g1[4], b1[4];
#pragma unroll
    for (int j = 0; j < 4; ++j) {
      w4[j] = *(const f32x4*)&pW1[128 * 256 + c * 16 + j * 4];
      g1[j] = *(const f32x4*)&pln1_g[c * 16 + j * 4];
      b1[j] = *(const f32x4*)&pln1_b[c * 16 + j * 4];
    }
    float sw = 0.f, sw2 = 0.f;
#pragma unroll
    for (int j = 0; j < 4; ++j)
#pragma unroll
      for (int u = 0; u < 4; ++u) {
        sw += w4[j][u];
        sw2 = fmaf(w4[j][u], w4[j][u], sw2);
      }
#pragma unroll
    for (int m = 1; m < 16; m <<= 1) {
      sw += __shfl_xor(sw, m);
      sw2 += __shfl_xor(sw2, m);
    }
    const float mw = sw * (1.f / 256.f), e2w = sw2 * (1.f / 256.f);
    f32x4 stc = *(const f32x4*)&nvstats[n_pre[0] * 4];
    f32x4 nvc[4];
#pragma unroll
    for (int j = 0; j < 4; ++j)
      nvc[j] = *(const f32x4*)&nvphi[(size_t)n_pre[0] * 256 + c * 16 + j * 4];
#pragma unroll
    for (int rd = 0; rd < 4; ++rd) {
      f32x4 stn;
      f32x4 nvn[4];
      if (rd < 3) {
        stn = *(const f32x4*)&nvstats[n_pre[rd + 1] * 4];
#pragma unroll
        for (int j = 0; j < 4; ++j)
          nvn[j] = *(const f32x4*)&nvphi[(size_t)n_pre[rd + 1] * 256 + c * 16 + j * 4];
      }
      const int p = w * 16 + rd * 4 + q;
      const float a = a_pre[rd];
      const float mu = fmaf(a, mw, stc.x);
      const float e2 = fmaf(a * a, e2w, fmaf(a + a, stc.z, stc.y));
      const float var = fmaxf(e2 - mu * mu, 0.f);
      const float rstd = 1.f / sqrtf(var + 1e-5f);
      const float nmr = -mu * rstd;
      unsigned pk[8];
#pragma unroll
      for (int j = 0; j < 4; ++j) {
        float hh[4];
#pragma unroll
        for (int u = 0; u < 4; ++u) {
          const float v = fmaf(a, w4[j][u], nvc[j][u]);
          const float tt = fmaf(v, rstd, nmr);
          hh[u] = gelu_tanh(fmaf(tt, g1[j][u], b1[j][u]));
        }
        pk[j * 2] = cvt_pk_bf16(hh[0], hh[1]);
        pk[j * 2 + 1] = cvt_pk_bf16(hh[2], hh[3]);
      }
      *(i32x4*)&h1s[p * 264 + c * 16] = (i32x4){(int)pk[0], (int)pk[1], (int)pk[2], (int)pk[3]};
      *(i32x4*)&h1s[p * 264 + c * 16 + 8] = (i32x4){(int)pk[4], (int)pk[5], (int)pk[6], (int)pk[7]};
      if (rd < 3) {
        stc = stn;
#pragma unroll
        for (int j = 0; j < 4; ++j) nvc[j] = nvn[j];
      }
    }
  }
  // ---- Phase B ----
  const u16* Bb = pW2T + ((size_t)(w * 64 + c) << 8) + q * 8;
  short8 be[4], bo[4];
#pragma unroll
  for (int nt = 0; nt < 4; ++nt) be[nt] = *(const short8*)&Bb[nt * 4096];
#pragma unroll
  for (int nt = 0; nt < 4; ++nt) bo[nt] = *(const short8*)&Bb[nt * 4096 + 32];
  f32x4 acc[4][4];
#pragma unroll
  for (int nt = 0; nt < 4; ++nt) {
    const float bz = pb2[w * 64 + nt * 16 + c];
#pragma unroll
    for (int mt = 0; mt < 4; ++mt) acc[mt][nt] = (f32x4){bz, bz, bz, bz};
  }
  __syncthreads();  // B2
#pragma unroll
  for (int ks2 = 0; ks2 < 4; ++ks2) {
    {
      short8 av[4];
#pragma unroll
      for (int mt = 0; mt < 4; ++mt)
        av[mt] = *(const short8*)&h1s[(mt * 16 + c) * 264 + ks2 * 64 + q * 8];
#pragma unroll
      for (int mt = 0; mt < 4; ++mt)
#pragma unroll
        for (int nt = 0; nt < 4; ++nt)
          acc[mt][nt] =
              __builtin_amdgcn_mfma_f32_16x16x32_bf16(av[mt], be[nt], acc[mt][nt], 0, 0, 0);
      if (ks2 < 3) {
#pragma unroll
        for (int nt = 0; nt < 4; ++nt)
          be[nt] = *(const short8*)&Bb[nt * 4096 + ks2 * 64 + 64];
      }
    }
    {
      short8 av[4];
#pragma unroll
      for (int mt = 0; mt < 4; ++mt)
        av[mt] = *(const short8*)&h1s[(mt * 16 + c) * 264 + ks2 * 64 + 32 + q * 8];
#pragma unroll
      for (int mt = 0; mt < 4; ++mt)
#pragma unroll
        for (int nt = 0; nt < 4; ++nt)
          acc[mt][nt] =
              __builtin_amdgcn_mfma_f32_16x16x32_bf16(av[mt], bo[nt], acc[mt][nt], 0, 0, 0);
      if (ks2 < 3) {
#pragma unroll
        for (int nt = 0; nt < 4; ++nt)
          bo[nt] = *(const short8*)&Bb[nt * 4096 + ks2 * 64 + 96];
      }
    }
  }
  __syncthreads();  // B3
  // ---- Phase C: LN2 stats via LDS transpose reduce ----
  float* sbuf = (float*)h1s;
  float* s2buf = sbuf + 64 * 66;
#pragma unroll
  for (int mt = 0; mt < 4; ++mt)
#pragma unroll
    for (int reg = 0; reg < 4; ++reg) {
      const float v0 = acc[mt][0][reg], v1 = acc[mt][1][reg];
      const float v2 = acc[mt][2][reg], v3 = acc[mt][3][reg];
      const float s = (v0 + v1) + (v2 + v3);
      float s2 = v0 * v0;
      s2 = fmaf(v1, v1, s2);
      s2 = fmaf(v2, v2, s2);
      s2 = fmaf(v3, v3, s2);
      const int r = mt * 16 + q * 4 + reg;
      sbuf[r * 66 + w * 16 + c] = s;
      s2buf[r * 66 + w * 16 + c] = s2;
    }
  __syncthreads();  // B4
  {
    const int r = tid >> 2, seg = tid & 3;
    const float* rp = &sbuf[r * 66 + seg * 16];
    const float* rp2 = &s2buf[r * 66 + seg * 16];
    float ss = 0.f, ss2 = 0.f;
#pragma unroll
    for (int j = 0; j < 8; ++j) {
      const f32x2 u = *(const f32x2*)&rp[j * 2];
      const f32x2 u2 = *(const f32x2*)&rp2[j * 2];
      ss += u[0] + u[1];
      ss2 += u2[0] + u2[1];
    }
    ss += __shfl_xor(ss, 1);
    ss2 += __shfl_xor(ss2, 1);
    ss += __shfl_xor(ss, 2);
    ss2 += __shfl_xor(ss2, 2);
    if (seg == 0) {
      const float mu = ss * (1.f / 256.f);
      const float var = fmaxf(ss2 * (1.f / 256.f) - mu * mu, 0.f);
      const float rstd = 1.f / sqrtf(var + 1e-5f);
      rowstats[r * 2] = mu;
      rowstats[r * 2 + 1] = rstd;
    }
  }
  __syncthreads();  // B5
  float g2v[4], b2v[4], aggl[4];
#pragma unroll
  for (int nt = 0; nt < 4; ++nt) {
    g2v[nt] = pln2_g[w * 64 + nt * 16 + c];
    b2v[nt] = pln2_b[w * 64 + nt * 16 + c];
    aggl[nt] = 16.f * b2v[nt];
  }
#pragma unroll
  for (int mt = 0; mt < 4; ++mt)
#pragma unroll
    for (int reg = 0; reg < 4; ++reg) {
      const int r = mt * 16 + q * 4 + reg;
      const f32x2 mr = *(const f32x2*)&rowstats[r * 2];
      const float nmr = -mr[0] * mr[1];
#pragma unroll
      for (int nt = 0; nt < 4; ++nt) {
        const float tt = fmaf(acc[mt][nt][reg], mr[1], nmr);
        aggl[nt] = fmaf(tt, g2v[nt], aggl[nt]);
      }
    }
  float* aggb = sbuf;
#pragma unroll
  for (int nt = 0; nt < 4; ++nt) {
    float vs = aggl[nt];
    vs += __shfl_xor(vs, 16);
    vs += __shfl_xor(vs, 32);
    if (q == 0) aggb[w * 64 + nt * 16 + c] = vs;
  }
  __syncthreads();  // B6
  const float v = aggb[tid];
  float s = v, s2 = v * v;
  waveRed2(s, s2);
  if ((tid & 63) == 0) { red[(tid >> 6) * 2] = s; red[(tid >> 6) * 2 + 1] = s2; }
  __syncthreads();  // B7
  s = red[0] + red[2] + red[4] + red[6];
  s2 = red[1] + red[3] + red[5] + red[7];
  const float mu = s * (1.f / 256.f);
  const float var = fmaxf(s2 * (1.f / 256.f) - mu * mu, 0.f);
  const float rstd = 1.f / sqrtf(var + 1e-5f);
  rh[(size_t)t * 256 + tid] = f2bf((v - mu) * rstd * rln_g[tid] + rln_b[tid]);
}

// ---------------- launch ----------------
extern "C" void kernel_launch(void* const* d_in, const int* in_sizes, int n_in,
                              void* d_out, int out_size, void* d_ws, size_t ws_size,
                              hipStream_t stream) {
  const float* x = (const float*)d_in[0];
  const float* W_in = (const float*)d_in[1];
  const float* nv = (const float*)d_in[2];
  const float* Wr1 = (const float*)d_in[3];
  const float* Wr2 = (const float*)d_in[4];
  const float* rn_g = (const float*)d_in[5];
  const float* rn_b = (const float*)d_in[6];
  const float* pW1 = (const float*)d_in[7];
  const float* pb1 = (const float*)d_in[8];
  const float* pln1_g = (const float*)d_in[9];
  const float* pln1_b = (const float*)d_in[10];
  const float* pW2 = (const float*)d_in[11];
  const float* pb2 = (const float*)d_in[12];
  const float* pln2_g = (const float*)d_in[13];
  const float* pln2_b = (const float*)d_in[14];
  const float* rln_g = (const float*)d_in[15];
  const float* rln_b = (const float*)d_in[16];
  const float* rW1 = (const float*)d_in[17];
  const float* rb1 = (const float*)d_in[18];
  const float* rW2 = (const float*)d_in[19];
  const float* rb2 = (const float*)d_in[20];
  float* out = (float*)d_out;
  const int T = in_sizes[0] / 512;  // 4096

  float* ws = (float*)d_ws;
  float* xln = ws;    ws += (size_t)T * 512;
  float* h = ws;      ws += (size_t)T * 512;
  float* nvphi = ws;  ws += (size_t)2048 * 256;
  float* nvstats = ws; ws += (size_t)2048 * 4;
  float* actb = ws;   ws += (size_t)T * 64;
  int* idx = (int*)ws;   ws += (size_t)T * 64;
  u16* scoresb = (u16*)ws; ws += (size_t)T * 2048 / 2;
  u16* hb = (u16*)ws;    ws += (size_t)T * 512 / 2;
  u16* Wr2b = (u16*)ws;  ws += (size_t)2048 * 512 / 2;
  u16* pW2T = (u16*)ws;  ws += (size_t)2048 * 256 / 2;
  u16* rh = (u16*)ws;    ws += (size_t)T * 256 / 2;
  u16* t1b = (u16*)ws;   ws += (size_t)T * 512 / 2;
  u16* rW1T = (u16*)ws;  ws += (size_t)512 * 256 / 2;
  u16* rW2T = (u16*)ws;  ws += (size_t)512 * 512 / 2;

  k_prep<<<5632 + T, 256, 0, stream>>>(nv, pW1, pb1, nvphi, nvstats, pW2, pW2T,
                                       rW1, rW1T, rW2, rW2T, Wr2, Wr2b, x, rn_g,
                                       rn_b, xln);
  gemm8f<2, true><<<dim3(512 / 64, T / 128), 256, 0, stream>>>(
      xln, Wr1, h, hb, T, 512, 512);
  gemm_mf<0, false, 1, 128><<<dim3(2048 / 128, T / 64), 256, 0, stream>>>(
      hb, Wr2b, nullptr, scoresb, T, 2048, 512);
  k_topk_act<<<T, 256, 0, stream>>>(scoresb, h, Wr2, x, W_in, idx, actb);
  k_phi<<<T, 256, 0, stream>>>(nvphi, nvstats, pW1, pln1_g, pln1_b, pW2T, pb2,
                               pln2_g, pln2_b, idx, actb, rln_g, rln_b, rh);
  gemm_mf<1, true, 1, 64><<<dim3(512 / 64, T / 64), 256, 0, stream>>>(
      rh, rW1T, rb1, t1b, T, 512, 256);
  gemm_mf<0, true, 0, 64><<<dim3(512 / 64, T / 64), 256, 0, stream>>>(
      t1b, rW2T, rb2, out, T, 512, 512);
}